// Round 1
// baseline (387.121 us; speedup 1.0000x reference)
//
#include <hip/hip_runtime.h>

#define D_   1024
#define H_   16
#define DHd  64
#define BLK  256
#define B_   4
#define S_   4096
#define NB_  16
#define M_   16384
#define N1_  3072

typedef __attribute__((ext_vector_type(8))) short short8;
typedef __attribute__((ext_vector_type(4))) float f32x4;
typedef unsigned short u16;
typedef __attribute__((ext_vector_type(4))) unsigned short u16x4;

__device__ inline u16 f2bf(float f) {
  unsigned int u = __float_as_uint(f);
  unsigned int r = (u + 0x7fffu + ((u >> 16) & 1u)) >> 16;
  return (u16)r;
}

__device__ inline void async_ld16(const void* g, void* l) {
  __builtin_amdgcn_global_load_lds(
      (const __attribute__((address_space(1))) unsigned int*)g,
      (__attribute__((address_space(3))) unsigned int*)l, 16, 0, 0);
}

// ---------------- prep: x[perm] -> bf16, permuted order ----------------
__global__ __launch_bounds__(256)
void permute_cast_kernel(const float* __restrict__ x, const int* __restrict__ perm,
                         u16* __restrict__ xp) {
  int bid = blockIdx.x;          // permuted-order row 0..16383
  int b = bid >> 12;
  int i = bid & 4095;
  int prow = perm[b * S_ + i];
  const float4* src = reinterpret_cast<const float4*>(x + (size_t)(b * S_ + prow) * D_);
  float4 v = src[threadIdx.x];
  u16x4 o;
  o.x = f2bf(v.x); o.y = f2bf(v.y); o.z = f2bf(v.z); o.w = f2bf(v.w);
  reinterpret_cast<u16x4*>(xp + (size_t)bid * D_)[threadIdx.x] = o;
}

// ---------------- weight transpose + cast: src[R][C] f32 -> dst[C][R] bf16 ----------------
__global__ __launch_bounds__(256)
void transpose_cast_kernel(const float* __restrict__ src, u16* __restrict__ dst,
                           int R, int C) {
  __shared__ float tile[32][33];
  int tx = threadIdx.x, ty = threadIdx.y;     // block (32,8)
  int c0 = blockIdx.x * 32, r0 = blockIdx.y * 32;
  #pragma unroll
  for (int i = ty; i < 32; i += 8)
    tile[i][tx] = src[(size_t)(r0 + i) * C + c0 + tx];
  __syncthreads();
  #pragma unroll
  for (int i = ty; i < 32; i += 8)
    dst[(size_t)(c0 + i) * R + r0 + tx] = f2bf(tile[tx][i]);
}

// ---------------- tiled bf16 MFMA GEMM, m97 structure ----------------
// A: [M][1024] bf16 (rows in permuted order).  BT: [N][1024] bf16 (B transposed, k-contig).
// MODE 0: qkv epilogue.  MODE 1: out-proj epilogue (scatter rows via perm).
template<int MODE>
__global__ __launch_bounds__(256)
void gemm_kernel(const u16* __restrict__ A, const u16* __restrict__ BT,
                 const float* __restrict__ bias, const int* __restrict__ perm,
                 u16* __restrict__ q_ws, u16* __restrict__ k_ws, u16* __restrict__ vT_ws,
                 float* __restrict__ out_k, float* __restrict__ out_v,
                 float* __restrict__ out_o) {
  __shared__ u16 Al[128 * 32];
  __shared__ u16 Bl[128 * 32];
  __shared__ int perm_l[128];

  const int tid  = threadIdx.x;
  const int lane = tid & 63;
  const int w    = tid >> 6;
  const int wm   = w >> 1, wn = w & 1;
  const int i0   = blockIdx.x * 128;
  const int n0   = blockIdx.y * 128;
  const int bidx = i0 >> 12;                 // batch (128-blocks never straddle S=4096)
  const int l4   = lane >> 4;
  const int l15  = lane & 15;
  const int lr   = lane >> 2;                // staging row-in-16
  const int lk   = (lane & 3) << 3;          // staging k offset (elements)

  if (tid < 128) perm_l[tid] = perm[bidx * S_ + (i0 & 4095) + tid];

  f32x4 acc[4][4] = {};

  #pragma unroll 2
  for (int kt = 0; kt < 1024; kt += 32) {
    #pragma unroll
    for (int c = 0; c < 2; ++c) {
      int rA = w * 32 + c * 16;
      async_ld16(A  + (size_t)(i0 + rA + lr) * 1024 + kt + lk, &Al[rA * 32]);
      async_ld16(BT + (size_t)(n0 + rA + lr) * 1024 + kt + lk, &Bl[rA * 32]);
    }
    __syncthreads();
    short8 af[4], bf[4];
    #pragma unroll
    for (int mt = 0; mt < 4; ++mt)
      af[mt] = *reinterpret_cast<const short8*>(&Al[(wm * 64 + mt * 16 + l15) * 32 + l4 * 8]);
    #pragma unroll
    for (int nt = 0; nt < 4; ++nt)
      bf[nt] = *reinterpret_cast<const short8*>(&Bl[(wn * 64 + nt * 16 + l15) * 32 + l4 * 8]);
    #pragma unroll
    for (int mt = 0; mt < 4; ++mt)
      #pragma unroll
      for (int nt = 0; nt < 4; ++nt)
        acc[mt][nt] = __builtin_amdgcn_mfma_f32_16x16x32_bf16(af[mt], bf[nt], acc[mt][nt], 0, 0, 0);
    __syncthreads();
  }

  // ---- epilogue ----  C layout: row=(lane>>4)*4+r (+16*mt), col=lane&15 (+16*nt)
  if (MODE == 0) {
    #pragma unroll
    for (int nt = 0; nt < 4; ++nt) {
      int col = n0 + wn * 64 + nt * 16 + l15;
      float bias_v = bias[col];
      int h  = col / 192;
      int rem = col - h * 192;
      int cc = rem >> 6;
      int dd = rem & 63;
      int qcol = (h << 6) + dd;
      #pragma unroll
      for (int mt = 0; mt < 4; ++mt) {
        int rbase = i0 + wm * 64 + mt * 16 + l4 * 4;
        if (cc == 0) {
          #pragma unroll
          for (int r = 0; r < 4; ++r) {
            float val = acc[mt][nt][r] + bias_v;
            q_ws[(size_t)(rbase + r) * D_ + qcol] = f2bf(val);
          }
        } else if (cc == 1) {
          #pragma unroll
          for (int r = 0; r < 4; ++r) {
            float val = acc[mt][nt][r] + bias_v;
            int rr = rbase + r;
            k_ws[(size_t)rr * D_ + qcol] = f2bf(val);
            int prow = perm_l[rr - i0];
            out_k[(size_t)(bidx * S_ + prow) * D_ + qcol] = val;
          }
        } else {
          u16x4 pk;
          #pragma unroll
          for (int r = 0; r < 4; ++r) {
            float val = acc[mt][nt][r] + bias_v;
            int rr = rbase + r;
            int prow = perm_l[rr - i0];
            out_v[(size_t)(bidx * S_ + prow) * D_ + qcol] = val;
            pk[r] = f2bf(val);
          }
          int i_loc = rbase & 4095;
          int nblk = i_loc >> 8;
          int t    = i_loc & 255;
          *reinterpret_cast<u16x4*>(
              &vT_ws[((((size_t)bidx * NB_ + nblk) * H_ + h) * DHd + dd) * BLK + t]) = pk;
        }
      }
    }
  } else {
    #pragma unroll
    for (int nt = 0; nt < 4; ++nt) {
      int col = n0 + wn * 64 + nt * 16 + l15;
      float bias_v = bias[col];
      #pragma unroll
      for (int mt = 0; mt < 4; ++mt) {
        int rbase = i0 + wm * 64 + mt * 16 + l4 * 4;
        #pragma unroll
        for (int r = 0; r < 4; ++r) {
          int rr = rbase + r;
          int prow = perm_l[rr - i0];
          out_o[(size_t)(bidx * S_ + prow) * D_ + col] = acc[mt][nt][r] + bias_v;
        }
      }
    }
  }
}

// ---------------- block attention: 1 block per (b, nblk, h), 4 waves x 64 rows ----------------
__global__ __launch_bounds__(256)
void attn_kernel(const u16* __restrict__ q_ws, const u16* __restrict__ k_ws,
                 const u16* __restrict__ vT_ws, u16* __restrict__ o_ws) {
  __shared__ u16 P_lds[4 * 64 * 64];   // per-wave 64x64 bf16 P tile

  int bid  = blockIdx.x;
  int h    = bid & 15;
  int nblk = (bid >> 4) & 15;
  int b    = bid >> 8;
  int row0 = b * S_ + nblk * BLK;      // global permuted-order row base
  int lane = threadIdx.x & 63;
  int w    = threadIdx.x >> 6;
  int l4 = lane >> 4, l15 = lane & 15;

  const u16* qb  = q_ws + (size_t)row0 * D_ + h * 64;
  const u16* kb  = k_ws + (size_t)row0 * D_ + h * 64;
  const u16* vTb = vT_ws + ((size_t)(b * NB_ + nblk) * H_ + h) * (size_t)(DHd * BLK);

  // Q fragments (A-layout: row = l&15, k = 8*(l>>4)+j), hoisted for all 4 col-tiles
  short8 qf[4][2];
  #pragma unroll
  for (int mt = 0; mt < 4; ++mt)
    #pragma unroll
    for (int kk = 0; kk < 2; ++kk)
      qf[mt][kk] = *reinterpret_cast<const short8*>(
          qb + (size_t)(w * 64 + mt * 16 + l15) * D_ + kk * 32 + l4 * 8);

  f32x4 Oacc[4][4] = {};
  float mS[4][4], lS[4][4];
  #pragma unroll
  for (int mt = 0; mt < 4; ++mt)
    #pragma unroll
    for (int r = 0; r < 4; ++r) { mS[mt][r] = -1e30f; lS[mt][r] = 0.f; }

  for (int ct = 0; ct < 4; ++ct) {
    // S = Q K^T  (scores for 64 q-rows x 64 keys)
    f32x4 Sc[4][4] = {};
    #pragma unroll
    for (int kk = 0; kk < 2; ++kk) {
      #pragma unroll
      for (int nt = 0; nt < 4; ++nt) {
        short8 kf = *reinterpret_cast<const short8*>(
            kb + (size_t)(ct * 64 + nt * 16 + l15) * D_ + kk * 32 + l4 * 8);
        #pragma unroll
        for (int mt = 0; mt < 4; ++mt)
          Sc[mt][nt] = __builtin_amdgcn_mfma_f32_16x16x32_bf16(qf[mt][kk], kf, Sc[mt][nt], 0, 0, 0);
      }
    }
    // online softmax (rows live on (mt,r), cols on (nt, l15); reduce over 16-lane group)
    #pragma unroll
    for (int mt = 0; mt < 4; ++mt) {
      #pragma unroll
      for (int r = 0; r < 4; ++r) {
        float v0 = fmaxf(fmaxf(Sc[mt][0][r], Sc[mt][1][r]), fmaxf(Sc[mt][2][r], Sc[mt][3][r]));
        v0 *= 0.125f;
        v0 = fmaxf(v0, __shfl_xor(v0, 1));
        v0 = fmaxf(v0, __shfl_xor(v0, 2));
        v0 = fmaxf(v0, __shfl_xor(v0, 4));
        v0 = fmaxf(v0, __shfl_xor(v0, 8));
        float mn = fmaxf(mS[mt][r], v0);
        float alpha = __expf(mS[mt][r] - mn);
        mS[mt][r] = mn;
        float rs = 0.f;
        #pragma unroll
        for (int nt = 0; nt < 4; ++nt) {
          float p = __expf(Sc[mt][nt][r] * 0.125f - mn);
          Sc[mt][nt][r] = p;
          rs += p;
        }
        rs += __shfl_xor(rs, 1);
        rs += __shfl_xor(rs, 2);
        rs += __shfl_xor(rs, 4);
        rs += __shfl_xor(rs, 8);
        lS[mt][r] = lS[mt][r] * alpha + rs;
        #pragma unroll
        for (int nt = 0; nt < 4; ++nt)
          Oacc[mt][nt][r] *= alpha;
      }
    }
    // P: C-layout -> LDS -> A-layout (per-wave slice; same-wave LDS ops are ordered)
    #pragma unroll
    for (int mt = 0; mt < 4; ++mt)
      #pragma unroll
      for (int nt = 0; nt < 4; ++nt)
        #pragma unroll
        for (int r = 0; r < 4; ++r)
          P_lds[w * 4096 + (mt * 16 + l4 * 4 + r) * 64 + nt * 16 + l15] = f2bf(Sc[mt][nt][r]);
    // O += P V   (V consumed via vT: k-contiguous)
    #pragma unroll
    for (int kk = 0; kk < 2; ++kk) {
      short8 pa[4];
      #pragma unroll
      for (int mt = 0; mt < 4; ++mt)
        pa[mt] = *reinterpret_cast<const short8*>(
            &P_lds[w * 4096 + (mt * 16 + l15) * 64 + kk * 32 + l4 * 8]);
      #pragma unroll
      for (int nt = 0; nt < 4; ++nt) {
        short8 vf = *reinterpret_cast<const short8*>(
            vTb + (size_t)(nt * 16 + l15) * BLK + ct * 64 + kk * 32 + l4 * 8);
        #pragma unroll
        for (int mt = 0; mt < 4; ++mt)
          Oacc[mt][nt] = __builtin_amdgcn_mfma_f32_16x16x32_bf16(pa[mt], vf, Oacc[mt][nt], 0, 0, 0);
      }
    }
  }
  // write O (merged-head [row][h*64+d], bf16, permuted order)
  u16* ob = o_ws + (size_t)row0 * D_ + h * 64;
  #pragma unroll
  for (int mt = 0; mt < 4; ++mt)
    #pragma unroll
    for (int r = 0; r < 4; ++r) {
      float inv = 1.f / lS[mt][r];
      int row = w * 64 + mt * 16 + l4 * 4 + r;
      #pragma unroll
      for (int nt = 0; nt < 4; ++nt)
        ob[(size_t)row * D_ + nt * 16 + l15] = f2bf(Oacc[mt][nt][r] * inv);
    }
}

extern "C" void kernel_launch(void* const* d_in, const int* in_sizes, int n_in,
                              void* d_out, int out_size, void* d_ws, size_t ws_size,
                              hipStream_t stream) {
  const float* x     = (const float*)d_in[0];
  const int*   perm  = (const int*)d_in[1];
  const float* W_in  = (const float*)d_in[2];
  const float* b_in  = (const float*)d_in[3];
  const float* W_out = (const float*)d_in[4];
  const float* b_out = (const float*)d_in[5];

  float* out_o = (float*)d_out;
  float* out_k = out_o + (size_t)M_ * D_;
  float* out_v = out_k + (size_t)M_ * D_;

  const size_t nE = (size_t)M_ * D_;
  u16 *xp, *q_ws, *k_ws, *vT, *o_ws, *WinT, *WoutT;
  size_t need_full = (5 * nE + (size_t)N1_ * D_ + (size_t)D_ * D_) * 2;
  if (ws_size >= need_full) {
    u16* w = (u16*)d_ws;
    xp = w; q_ws = xp + nE; k_ws = q_ws + nE; vT = k_ws + nE; o_ws = vT + nE;
    WinT = o_ws + nE; WoutT = WinT + (size_t)N1_ * D_;
  } else {
    // park xp/q_ws in the o-chunk of d_out (GEMM3 fully overwrites it last)
    xp = (u16*)d_out; q_ws = xp + nE;
    u16* w = (u16*)d_ws;
    k_ws = w; vT = k_ws + nE; o_ws = vT + nE;
    WinT = o_ws + nE; WoutT = WinT + (size_t)N1_ * D_;
  }

  permute_cast_kernel<<<M_, 256, 0, stream>>>(x, perm, xp);
  transpose_cast_kernel<<<dim3(N1_ / 32, D_ / 32), dim3(32, 8), 0, stream>>>(W_in, WinT, D_, N1_);
  transpose_cast_kernel<<<dim3(D_ / 32, D_ / 32), dim3(32, 8), 0, stream>>>(W_out, WoutT, D_, D_);
  gemm_kernel<0><<<dim3(M_ / 128, N1_ / 128), 256, 0, stream>>>(
      xp, WinT, b_in, perm, q_ws, k_ws, vT, out_k, out_v, nullptr);
  attn_kernel<<<B_ * NB_ * H_, 256, 0, stream>>>(q_ws, k_ws, vT, o_ws);
  gemm_kernel<1><<<dim3(M_ / 128, D_ / 128), 256, 0, stream>>>(
      o_ws, WoutT, b_out, perm, nullptr, nullptr, nullptr, nullptr, nullptr, out_o);
}

// Round 2
// 322.799 us; speedup vs baseline: 1.1993x; 1.1993x over previous
//
#include <hip/hip_runtime.h>

#define D_   1024
#define H_   16
#define DHd  64
#define BLK  256
#define B_   4
#define S_   4096
#define NB_  16
#define M_   16384
#define N1_  3072
#define NT_  32          // K tiles of 32

typedef __attribute__((ext_vector_type(8))) short short8;
typedef __attribute__((ext_vector_type(4))) float f32x4;
typedef unsigned short u16;
typedef __attribute__((ext_vector_type(4))) unsigned short u16x4;

__device__ inline u16 f2bf(float f) {
  unsigned int u = __float_as_uint(f);
  unsigned int r = (u + 0x7fffu + ((u >> 16) & 1u)) >> 16;
  return (u16)r;
}

__device__ inline void async_ld16(const void* g, void* l) {
  __builtin_amdgcn_global_load_lds(
      (const __attribute__((address_space(1))) unsigned int*)g,
      (__attribute__((address_space(3))) unsigned int*)l, 16, 0, 0);
}

// ---------------- prep: x[perm] -> bf16, permuted order ----------------
__global__ __launch_bounds__(256)
void permute_cast_kernel(const float* __restrict__ x, const int* __restrict__ perm,
                         u16* __restrict__ xp) {
  int bid = blockIdx.x;
  int b = bid >> 12;
  int i = bid & 4095;
  int prow = perm[b * S_ + i];
  const float4* src = reinterpret_cast<const float4*>(x + (size_t)(b * S_ + prow) * D_);
  float4 v = src[threadIdx.x];
  u16x4 o;
  o.x = f2bf(v.x); o.y = f2bf(v.y); o.z = f2bf(v.z); o.w = f2bf(v.w);
  reinterpret_cast<u16x4*>(xp + (size_t)bid * D_)[threadIdx.x] = o;
}

// ---------------- weight transpose + cast: src[R][C] f32 -> dst[C][R] bf16 ----------------
__global__ __launch_bounds__(256)
void transpose_cast_kernel(const float* __restrict__ src, u16* __restrict__ dst,
                           int R, int C) {
  __shared__ float tile[32][33];
  int tx = threadIdx.x, ty = threadIdx.y;     // block (32,8)
  int c0 = blockIdx.x * 32, r0 = blockIdx.y * 32;
  #pragma unroll
  for (int i = ty; i < 32; i += 8)
    tile[i][tx] = src[(size_t)(r0 + i) * C + c0 + tx];
  __syncthreads();
  #pragma unroll
  for (int i = ty; i < 32; i += 8)
    dst[(size_t)(c0 + i) * R + r0 + tx] = f2bf(tile[tx][i]);
}

// ---------------- 256x256-tile bf16 MFMA GEMM, depth-2 counted-vmcnt pipeline ----------------
// A: [M][1024] bf16 (permuted-order rows).  BT: [N][1024] bf16 (k-contiguous).
// 8 waves (2M x 4N), per-wave output 128x64.  BK=32, 4 LDS buffers (128 KiB).
// LDS tile per buffer: A[256][32] + B[256][32] u16, 16B-slot XOR-swizzled
// (phys_slot = logical_slot ^ ((row>>1)&3)) on BOTH the global_load_lds source
// and the ds_read address (rule 21).
template<int MODE>
__global__ __launch_bounds__(512, 2)
void gemm_kernel(const u16* __restrict__ A, const u16* __restrict__ BT,
                 const float* __restrict__ bias, const int* __restrict__ perm,
                 u16* __restrict__ q_ws, u16* __restrict__ k_ws, u16* __restrict__ vT_ws,
                 float* __restrict__ out_k, float* __restrict__ out_v,
                 float* __restrict__ out_o) {
  constexpr int NCOL = (MODE == 0) ? N1_ : D_;
  constexpr int NWG  = (M_ / 256) * (NCOL / 256);
  constexpr int CPX  = NWG / 8;               // NWG % 8 == 0 for both modes

  __shared__ u16 LDS[4 * 16384];              // 128 KiB: 4 bufs x (A 16KB + B 16KB)
  __shared__ int perm_l[256];

  const int tid  = threadIdx.x;
  const int lane = tid & 63;
  const int w    = tid >> 6;
  const int wr   = w >> 2, wc = w & 3;        // 2 x 4 wave grid
  const int l4   = lane >> 4, l15 = lane & 15;

  // XCD-aware bijective swizzle on flat block id
  const int orig = blockIdx.x;
  const int lid  = (orig & 7) * CPX + (orig >> 3);
  const int i0   = (lid & 63) * 256;          // M/256 == 64
  const int n0   = (lid >> 6) * 256;
  const int bidx = i0 >> 12;

  if (tid < 256) perm_l[tid] = perm[bidx * S_ + (i0 & 4095) + tid];

  // --- staging setup: thread t writes linear LDS slot, loads swizzled source ---
  const int srow = tid >> 2;                          // 0..127 within half
  const int sq   = (tid & 3) ^ ((tid >> 3) & 3);      // pre-swizzled logical slot
  const u16* pA0 = A  + (size_t)(i0 + srow) * 1024 + sq * 8;
  const u16* pA1 = pA0 + (size_t)128 * 1024;
  const u16* pB0 = BT + (size_t)(n0 + srow) * 1024 + sq * 8;
  const u16* pB1 = pB0 + (size_t)128 * 1024;

  // --- reader setup (byte offsets within a buffer) ---
  const int ps   = l4 ^ ((l15 >> 1) & 3);             // swizzled 16B slot
  const int aoff = (wr * 128 + l15) * 64 + ps * 16;
  const int boff = 16384 + (wc * 64 + l15) * 64 + ps * 16;

  f32x4 acc[8][4] = {};

  #define STAGE(kt, b) do {                                    \
    const int ko_ = (kt) * 32;                                 \
    u16* base_ = &LDS[(b) * 16384 + w * 512];                  \
    async_ld16(pA0 + ko_, base_);                              \
    async_ld16(pA1 + ko_, base_ + 4096);                       \
    async_ld16(pB0 + ko_, base_ + 8192);                       \
    async_ld16(pB1 + ko_, base_ + 12288);                      \
  } while (0)

  #define COMPUTE(b) do {                                                         \
    const char* lb_ = (const char*)LDS + (b) * 32768;                             \
    short8 af_[8], bf_[4];                                                        \
    _Pragma("unroll")                                                             \
    for (int m = 0; m < 8; ++m)                                                   \
      af_[m] = *reinterpret_cast<const short8*>(lb_ + aoff + m * 1024);           \
    bf_[0] = *reinterpret_cast<const short8*>(lb_ + boff);                        \
    bf_[1] = *reinterpret_cast<const short8*>(lb_ + boff + 1024);                 \
    __builtin_amdgcn_s_setprio(1);                                                \
    _Pragma("unroll")                                                             \
    for (int m = 0; m < 8; ++m) {                                                 \
      acc[m][0] = __builtin_amdgcn_mfma_f32_16x16x32_bf16(af_[m], bf_[0], acc[m][0], 0, 0, 0); \
      acc[m][1] = __builtin_amdgcn_mfma_f32_16x16x32_bf16(af_[m], bf_[1], acc[m][1], 0, 0, 0); \
    }                                                                             \
    __builtin_amdgcn_s_setprio(0);                                                \
    bf_[2] = *reinterpret_cast<const short8*>(lb_ + boff + 2048);                 \
    bf_[3] = *reinterpret_cast<const short8*>(lb_ + boff + 3072);                 \
    __builtin_amdgcn_s_setprio(1);                                                \
    _Pragma("unroll")                                                             \
    for (int m = 0; m < 8; ++m) {                                                 \
      acc[m][2] = __builtin_amdgcn_mfma_f32_16x16x32_bf16(af_[m], bf_[2], acc[m][2], 0, 0, 0); \
      acc[m][3] = __builtin_amdgcn_mfma_f32_16x16x32_bf16(af_[m], bf_[3], acc[m][3], 0, 0, 0); \
    }                                                                             \
    __builtin_amdgcn_s_setprio(0);                                                \
  } while (0)

  STAGE(0, 0);
  STAGE(1, 1);
  #pragma unroll 1
  for (int kt = 0; kt < NT_ - 2; ++kt) {
    STAGE(kt + 2, (kt + 2) & 3);
    // counted wait: tile kt's 4 loads (issued 2 iters ago) must land; tiles
    // kt+1/kt+2 (8 loads) stay in flight across the barrier. lgkmcnt(0)
    // retires our previous ds_reads before the buffer they read is recycled.
    asm volatile("s_waitcnt vmcnt(8) lgkmcnt(0)" ::: "memory");
    __builtin_amdgcn_s_barrier();
    COMPUTE(kt & 3);
  }
  asm volatile("s_waitcnt vmcnt(4) lgkmcnt(0)" ::: "memory");
  __builtin_amdgcn_s_barrier();
  COMPUTE((NT_ - 2) & 3);
  asm volatile("s_waitcnt vmcnt(0) lgkmcnt(0)" ::: "memory");
  __builtin_amdgcn_s_barrier();
  COMPUTE((NT_ - 1) & 3);
  #undef STAGE
  #undef COMPUTE

  // ---- epilogue ----  C layout: row = (lane>>4)*4 + r (+16*m), col = lane&15 (+16*n)
  if (MODE == 0) {
    #pragma unroll
    for (int n = 0; n < 4; ++n) {
      int col = n0 + wc * 64 + n * 16 + l15;
      float bias_v = bias[col];
      int h  = col / 192;
      int rem = col - h * 192;
      int cc = rem >> 6;
      int dd = rem & 63;
      int qcol = (h << 6) + dd;
      #pragma unroll
      for (int m = 0; m < 8; ++m) {
        int rbase = i0 + wr * 128 + m * 16 + l4 * 4;
        if (cc == 0) {
          #pragma unroll
          for (int r = 0; r < 4; ++r) {
            float val = acc[m][n][r] + bias_v;
            q_ws[(size_t)(rbase + r) * D_ + qcol] = f2bf(val);
          }
        } else if (cc == 1) {
          #pragma unroll
          for (int r = 0; r < 4; ++r) {
            float val = acc[m][n][r] + bias_v;
            int rr = rbase + r;
            k_ws[(size_t)rr * D_ + qcol] = f2bf(val);
            int prow = perm_l[rr - i0];
            out_k[(size_t)(bidx * S_ + prow) * D_ + qcol] = val;
          }
        } else {
          u16x4 pk;
          #pragma unroll
          for (int r = 0; r < 4; ++r) {
            float val = acc[m][n][r] + bias_v;
            int rr = rbase + r;
            int prow = perm_l[rr - i0];
            out_v[(size_t)(bidx * S_ + prow) * D_ + qcol] = val;
            pk[r] = f2bf(val);
          }
          int i_loc = rbase & 4095;
          int nblk = i_loc >> 8;
          int t    = i_loc & 255;
          *reinterpret_cast<u16x4*>(
              &vT_ws[((((size_t)bidx * NB_ + nblk) * H_ + h) * DHd + dd) * BLK + t]) = pk;
        }
      }
    }
  } else {
    #pragma unroll
    for (int n = 0; n < 4; ++n) {
      int col = n0 + wc * 64 + n * 16 + l15;
      float bias_v = bias[col];
      #pragma unroll
      for (int m = 0; m < 8; ++m) {
        int rbase = i0 + wr * 128 + m * 16 + l4 * 4;
        #pragma unroll
        for (int r = 0; r < 4; ++r) {
          int rr = rbase + r;
          int prow = perm_l[rr - i0];
          out_o[(size_t)(bidx * S_ + prow) * D_ + col] = acc[m][n][r] + bias_v;
        }
      }
    }
  }
}

// ---------------- block attention: 1 block per (b, nblk, h), 4 waves x 64 rows ----------------
__global__ __launch_bounds__(256)
void attn_kernel(const u16* __restrict__ q_ws, const u16* __restrict__ k_ws,
                 const u16* __restrict__ vT_ws, u16* __restrict__ o_ws) {
  __shared__ u16 P_lds[4 * 64 * 64];   // per-wave 64x64 bf16 P tile

  int bid  = blockIdx.x;
  int h    = bid & 15;
  int nblk = (bid >> 4) & 15;
  int b    = bid >> 8;
  int row0 = b * S_ + nblk * BLK;
  int lane = threadIdx.x & 63;
  int w    = threadIdx.x >> 6;
  int l4 = lane >> 4, l15 = lane & 15;

  const u16* qb  = q_ws + (size_t)row0 * D_ + h * 64;
  const u16* kb  = k_ws + (size_t)row0 * D_ + h * 64;
  const u16* vTb = vT_ws + ((size_t)(b * NB_ + nblk) * H_ + h) * (size_t)(DHd * BLK);

  short8 qf[4][2];
  #pragma unroll
  for (int mt = 0; mt < 4; ++mt)
    #pragma unroll
    for (int kk = 0; kk < 2; ++kk)
      qf[mt][kk] = *reinterpret_cast<const short8*>(
          qb + (size_t)(w * 64 + mt * 16 + l15) * D_ + kk * 32 + l4 * 8);

  f32x4 Oacc[4][4] = {};
  float mS[4][4], lS[4][4];
  #pragma unroll
  for (int mt = 0; mt < 4; ++mt)
    #pragma unroll
    for (int r = 0; r < 4; ++r) { mS[mt][r] = -1e30f; lS[mt][r] = 0.f; }

  for (int ct = 0; ct < 4; ++ct) {
    f32x4 Sc[4][4] = {};
    #pragma unroll
    for (int kk = 0; kk < 2; ++kk) {
      #pragma unroll
      for (int nt = 0; nt < 4; ++nt) {
        short8 kf = *reinterpret_cast<const short8*>(
            kb + (size_t)(ct * 64 + nt * 16 + l15) * D_ + kk * 32 + l4 * 8);
        #pragma unroll
        for (int mt = 0; mt < 4; ++mt)
          Sc[mt][nt] = __builtin_amdgcn_mfma_f32_16x16x32_bf16(qf[mt][kk], kf, Sc[mt][nt], 0, 0, 0);
      }
    }
    #pragma unroll
    for (int mt = 0; mt < 4; ++mt) {
      #pragma unroll
      for (int r = 0; r < 4; ++r) {
        float v0 = fmaxf(fmaxf(Sc[mt][0][r], Sc[mt][1][r]), fmaxf(Sc[mt][2][r], Sc[mt][3][r]));
        v0 *= 0.125f;
        v0 = fmaxf(v0, __shfl_xor(v0, 1));
        v0 = fmaxf(v0, __shfl_xor(v0, 2));
        v0 = fmaxf(v0, __shfl_xor(v0, 4));
        v0 = fmaxf(v0, __shfl_xor(v0, 8));
        float mn = fmaxf(mS[mt][r], v0);
        float alpha = __expf(mS[mt][r] - mn);
        mS[mt][r] = mn;
        float rs = 0.f;
        #pragma unroll
        for (int nt = 0; nt < 4; ++nt) {
          float p = __expf(Sc[mt][nt][r] * 0.125f - mn);
          Sc[mt][nt][r] = p;
          rs += p;
        }
        rs += __shfl_xor(rs, 1);
        rs += __shfl_xor(rs, 2);
        rs += __shfl_xor(rs, 4);
        rs += __shfl_xor(rs, 8);
        lS[mt][r] = lS[mt][r] * alpha + rs;
        #pragma unroll
        for (int nt = 0; nt < 4; ++nt)
          Oacc[mt][nt][r] *= alpha;
      }
    }
    #pragma unroll
    for (int mt = 0; mt < 4; ++mt)
      #pragma unroll
      for (int nt = 0; nt < 4; ++nt)
        #pragma unroll
        for (int r = 0; r < 4; ++r)
          P_lds[w * 4096 + (mt * 16 + l4 * 4 + r) * 64 + nt * 16 + l15] = f2bf(Sc[mt][nt][r]);
    #pragma unroll
    for (int kk = 0; kk < 2; ++kk) {
      short8 pa[4];
      #pragma unroll
      for (int mt = 0; mt < 4; ++mt)
        pa[mt] = *reinterpret_cast<const short8*>(
            &P_lds[w * 4096 + (mt * 16 + l15) * 64 + kk * 32 + l4 * 8]);
      #pragma unroll
      for (int nt = 0; nt < 4; ++nt) {
        short8 vf = *reinterpret_cast<const short8*>(
            vTb + (size_t)(nt * 16 + l15) * BLK + ct * 64 + kk * 32 + l4 * 8);
        #pragma unroll
        for (int mt = 0; mt < 4; ++mt)
          Oacc[mt][nt] = __builtin_amdgcn_mfma_f32_16x16x32_bf16(pa[mt], vf, Oacc[mt][nt], 0, 0, 0);
      }
    }
  }
  u16* ob = o_ws + (size_t)row0 * D_ + h * 64;
  #pragma unroll
  for (int mt = 0; mt < 4; ++mt)
    #pragma unroll
    for (int r = 0; r < 4; ++r) {
      float inv = 1.f / lS[mt][r];
      int row = w * 64 + mt * 16 + l4 * 4 + r;
      #pragma unroll
      for (int nt = 0; nt < 4; ++nt)
        ob[(size_t)row * D_ + nt * 16 + l15] = f2bf(Oacc[mt][nt][r] * inv);
    }
}

extern "C" void kernel_launch(void* const* d_in, const int* in_sizes, int n_in,
                              void* d_out, int out_size, void* d_ws, size_t ws_size,
                              hipStream_t stream) {
  const float* x     = (const float*)d_in[0];
  const int*   perm  = (const int*)d_in[1];
  const float* W_in  = (const float*)d_in[2];
  const float* b_in  = (const float*)d_in[3];
  const float* W_out = (const float*)d_in[4];
  const float* b_out = (const float*)d_in[5];

  float* out_o = (float*)d_out;
  float* out_k = out_o + (size_t)M_ * D_;
  float* out_v = out_k + (size_t)M_ * D_;

  const size_t nE = (size_t)M_ * D_;
  u16 *xp, *q_ws, *k_ws, *vT, *o_ws, *WinT, *WoutT;
  size_t need_full = (5 * nE + (size_t)N1_ * D_ + (size_t)D_ * D_) * 2;
  if (ws_size >= need_full) {
    u16* w = (u16*)d_ws;
    xp = w; q_ws = xp + nE; k_ws = q_ws + nE; vT = k_ws + nE; o_ws = vT + nE;
    WinT = o_ws + nE; WoutT = WinT + (size_t)N1_ * D_;
  } else {
    // park xp/q_ws in the o-chunk of d_out (GEMM3 fully overwrites it last)
    xp = (u16*)d_out; q_ws = xp + nE;
    u16* w = (u16*)d_ws;
    k_ws = w; vT = k_ws + nE; o_ws = vT + nE;
    WinT = o_ws + nE; WoutT = WinT + (size_t)N1_ * D_;
  }

  permute_cast_kernel<<<M_, 256, 0, stream>>>(x, perm, xp);
  transpose_cast_kernel<<<dim3(N1_ / 32, D_ / 32), dim3(32, 8), 0, stream>>>(W_in, WinT, D_, N1_);
  transpose_cast_kernel<<<dim3(D_ / 32, D_ / 32), dim3(32, 8), 0, stream>>>(W_out, WoutT, D_, D_);
  gemm_kernel<0><<<(M_ / 256) * (N1_ / 256), 512, 0, stream>>>(
      xp, WinT, b_in, perm, q_ws, k_ws, vT, out_k, out_v, nullptr);
  attn_kernel<<<B_ * NB_ * H_, 256, 0, stream>>>(q_ws, k_ws, vT, o_ws);
  gemm_kernel<1><<<(M_ / 256) * (D_ / 256), 512, 0, stream>>>(
      o_ws, WoutT, b_out, perm, nullptr, nullptr, nullptr, nullptr, nullptr, out_o);
}